// Round 8
// baseline (694.344 us; speedup 1.0000x reference)
//
#include <hip/hip_runtime.h>

// Perona-Malik diffusion, 500 iters = 50 launches x 10 wave-autonomous steps.
// Round-8: the per-iteration __syncthreads + LDS round trip is the measured
// invariant cost (~1 us/iter regardless of op count / fusion / occupancy).
// Fix: trapezoidal wave blocking — each wave holds a 64-col x 28-row region
// in registers (1 float/lane/row), exchanges horizontally via __shfl (pull),
// vertically via its own registers. Valid region shrinks 1 px/side/iter;
// 44x8 core exact after 10 iters. ZERO barriers, ZERO LDS in the loop.

#define HH 512
#define WW 512
#define NB 2
static constexpr float LAM   = 0.24f;
static constexpr float KCOND = 0.03f;
static constexpr float DEPS_ = 0.1f;
static constexpr int IMG      = HH * WW;
static constexpr int N_DEPTH  = NB * IMG;
static constexpr int CV_PER_B = (HH - 1) * WW;
static constexpr int CH_PER_B = HH * (WW - 1);
static constexpr int N_CV     = NB * CV_PER_B;
static constexpr int N_CH     = NB * CH_PER_B;

// ---- fast path: wave trapezoids ----
static constexpr int T_FUSE = 10, NSS = 50;        // 50 x 10 = 500
static constexpr int R_OUT  = 8;                   // output rows per wave
static constexpr int VTRAP  = T_FUSE;              // vertical halo
static constexpr int ROWS   = R_OUT + 2 * VTRAP;   // 28 register rows
static constexpr int CORE_W = 64 - 2 * T_FUSE;     // 44 valid cols
static constexpr int NSTRIP = 12;                  // 12*44 = 528 >= 512
static constexpr int NBANDY = HH / R_OUT;          // 64
static constexpr int NWAVE  = NSTRIP * NBANDY * NB;  // 1536
static constexpr int NT     = 256;                 // 4 waves/block
static constexpr int NBLK   = NWAVE / (NT / 64);   // 384

// global zero-padded coefficient planes
static constexpr int PAD  = 32;                    // covers strip overhang (gx up to 537)
static constexpr int PSTR = WW + 2 * PAD;          // 576
static constexpr int PV_SZ = (HH + 2 * PAD + 1) * PSTR;
static constexpr int PH_SZ = (HH + 2 * PAD) * PSTR;
static constexpr int PLANE_IMG = PV_SZ + PH_SZ;

// ---- fallback geometry (round-2 verified, T=10, inline gather) ----
static constexpr int TILE_WF = 64, TILE_HF = 32;
static constexpr int HALO_XF = 12, HALO_YF = 10;
static constexpr int RW_F = TILE_WF + 2 * HALO_XF;  // 88
static constexpr int RH_F = TILE_HF + 2 * HALO_YF;  // 52
static constexpr int NQ_ROW_F = RW_F / 4;           // 22
static constexpr int NQUAD_F  = NQ_ROW_F * RH_F;
static constexpr int QPT_F    = 5;
static constexpr int SSZ_F    = (RH_F + 2) * RW_F;

// ---- monotone float<->uint key for atomic min ----
__device__ __forceinline__ unsigned fkey(float f) {
    unsigned u = __float_as_uint(f);
    return (u & 0x80000000u) ? ~u : (u | 0x80000000u);
}
__device__ __forceinline__ float kinv(unsigned k) {
    return __uint_as_float((k & 0x80000000u) ? (k & 0x7fffffffu) : ~k);
}

__global__ void init_key_kernel(unsigned* key) { *key = 0xFFFFFFFFu; }

__global__ void min_kernel(const float* __restrict__ x, unsigned* key) {
    float m = 3.4e38f;
    for (int idx = blockIdx.x * blockDim.x + threadIdx.x; idx < N_DEPTH;
         idx += gridDim.x * blockDim.x)
        m = fminf(m, x[idx]);
    for (int off = 32; off > 0; off >>= 1) m = fminf(m, __shfl_down(m, off, 64));
    __shared__ float sm[4];
    int lane = threadIdx.x & 63, wv = threadIdx.x >> 6;
    if (lane == 0) sm[wv] = m;
    __syncthreads();
    if (threadIdx.x == 0) {
        float mm = fminf(fminf(sm[0], sm[1]), fminf(sm[2], sm[3]));
        atomicMin(key, fkey(mm));
    }
}

__global__ void coeff_kernel(const float* __restrict__ g, float* __restrict__ cv,
                             float* __restrict__ chh) {
    int idx = blockIdx.x * blockDim.x + threadIdx.x;
    constexpr float kk = KCOND * KCOND;
    if (idx < N_CV) {
        int b = idx / CV_PER_B;
        int r = idx - b * CV_PER_B;
        int i = r >> 9, j = r & (WW - 1);
        const float* gb = g + b * 3 * IMG + i * WW + j;
        float s = 0.f;
#pragma unroll
        for (int c = 0; c < 3; ++c) s += fabsf(gb[c * IMG + WW] - gb[c * IMG]);
        float m = s / 3.0f;
        cv[idx] = 1.0f / (1.0f + (m * m) / kk);
    } else if (idx < N_CV + N_CH) {
        int t = idx - N_CV;
        int b = t / CH_PER_B;
        int r = t - b * CH_PER_B;
        int i = r / (WW - 1);
        int j = r - i * (WW - 1);
        const float* gb = g + b * 3 * IMG + i * WW + j;
        float s = 0.f;
#pragma unroll
        for (int c = 0; c < 3; ++c) s += fabsf(gb[c * IMG + 1] - gb[c * IMG]);
        float m = s / 3.0f;
        chh[t] = 1.0f / (1.0f + (m * m) / kk);
    }
}

// One-time: global zero-padded L*cv / L*ch planes, stride PSTR.
// PV[(gy+PAD)*PSTR + gx+PAD] = L*cv of vertical edge ABOVE image row gy
//   (0 unless 1<=gy<=HH-1, 0<=gx<WW).
// PH[(gy+PAD)*PSTR + gxe+PAD] = L*ch of horizontal edge whose RIGHT px is gxe
//   (0 unless 0<=gy<HH, 1<=gxe<WW).
__global__ void prep_planes(const float* __restrict__ cv_g,
                            const float* __restrict__ ch_g,
                            float* __restrict__ planes) {
    int idx = blockIdx.x * blockDim.x + threadIdx.x;
    int total = NB * PLANE_IMG;
    if (idx >= total) return;
    int b = idx / PLANE_IMG;
    int r = idx - b * PLANE_IMG;
    float* dst = planes + b * PLANE_IMG;
    if (r < PV_SZ) {
        int row = r / PSTR, col = r - row * PSTR;
        int gy = row - PAD, gx = col - PAD;
        bool ok = (gy >= 1) && (gy <= HH - 1) && (gx >= 0) && (gx < WW);
        dst[r] = ok ? LAM * cv_g[b * CV_PER_B + (gy - 1) * WW + gx] : 0.f;
    } else {
        int rr = r - PV_SZ;
        int row = rr / PSTR, col = rr - row * PSTR;
        int gy = row - PAD, gxe = col - PAD;
        bool ok = (gy >= 0) && (gy < HH) && (gxe >= 1) && (gxe < WW);
        dst[r] = ok ? LAM * ch_g[b * CH_PER_B + gy * (WW - 1) + (gxe - 1)] : 0.f;
    }
}

template <bool ADD_SHIFT, bool SUB_SHIFT>
__global__ __launch_bounds__(NT) void step_wave(
    const float* __restrict__ src, float* __restrict__ dst,
    const float* __restrict__ planes, const unsigned* __restrict__ key) {
    const int wid  = blockIdx.x * (NT / 64) + (threadIdx.x >> 6);
    const int lane = threadIdx.x & 63;
    const int s    = wid % NSTRIP;
    const int rest = wid / NSTRIP;
    const int band = rest % NBANDY;
    const int img  = rest / NBANDY;

    const int gx  = s * CORE_W - T_FUSE + lane;   // -10 .. 537
    const int gy0 = band * R_OUT - VTRAP;         // -10 .. 494

    const float* srcb = src + img * IMG;
    const float* PVb  = planes + img * PLANE_IMG;
    const float* PHb  = PVb + PV_SZ;

    float shift = 0.f;
    if (ADD_SHIFT || SUB_SHIFT) shift = (kinv(*key) <= DEPS_) ? DEPS_ : 0.f;

    float v[ROWS], vert[ROWS + 1], chl[ROWS], chr[ROWS], cc[ROWS];

    const int pbase = (gy0 + PAD) * PSTR + (gx + PAD);
    const bool gxin = (unsigned)gx < (unsigned)WW;

    // ---- setup: coalesced loads (planes are padded -> no predication) ----
#pragma unroll
    for (int k = 0; k < ROWS + 1; ++k) vert[k] = PVb[pbase + k * PSTR];
#pragma unroll
    for (int k = 0; k < ROWS; ++k) chl[k] = PHb[pbase + k * PSTR];
#pragma unroll
    for (int k = 0; k < ROWS; ++k) chr[k] = __shfl_down(chl[k], 1);
#pragma unroll
    for (int k = 0; k < ROWS; ++k)
        cc[k] = 1.f - (vert[k] + vert[k + 1] + chl[k] + chr[k]);
#pragma unroll
    for (int k = 0; k < ROWS; ++k) {
        int gy = gy0 + k;
        bool in = gxin && ((unsigned)gy < (unsigned)HH);
        float val = in ? srcb[gy * WW + gx] : 0.f;
        if (ADD_SHIFT) val = in ? val + shift : 0.f;
        v[k] = val;
    }

    // ---- 10 iterations, zero barriers, zero LDS buffers ----
    // valid rows at count t: [t, ROWS-1-t]; valid lanes: [t, 63-t].
    // edge-lane shuffle garbage corrupts only lanes leaving the trapezoid.
#pragma unroll
    for (int it = 0; it < T_FUSE; ++it) {
        float prev = v[it];                       // old v[k-1] for row it+1
#pragma unroll
        for (int k = it + 1; k <= ROWS - 2 - it; ++k) {
            float ll = __shfl_up(v[k], 1);
            float rr = __shfl_down(v[k], 1);
            float nv = cc[k] * v[k] + vert[k] * prev + vert[k + 1] * v[k + 1] +
                       chl[k] * ll + chr[k] * rr;
            prev = v[k];
            v[k] = nv;
        }
    }

    // ---- store the exact 44x8 core ----
    float* dstb = dst + img * IMG;
    if (lane >= T_FUSE && lane < T_FUSE + CORE_W && gx < WW) {
#pragma unroll
        for (int k = VTRAP; k < VTRAP + R_OUT; ++k) {
            float o = v[k];
            if (SUB_SHIFT) o -= shift;
            dstb[(gy0 + k) * WW + gx] = o;
        }
    }
}

// -------- fallback (round-2 verified, inline gather, 256 threads) --------
template <bool ADD_SHIFT, bool SUB_SHIFT>
__global__ __launch_bounds__(256, 1) void step_fused(
    const float* __restrict__ src, float* __restrict__ dst,
    const float* __restrict__ cv_g, const float* __restrict__ ch_g,
    const unsigned* __restrict__ key) {
    __shared__ float sb[2][SSZ_F];
    const int blk = blockIdx.x;
    const int b = blk >> 7, t = blk & 127;
    const int y0 = (t >> 3) * TILE_HF, x0 = (t & 7) * TILE_WF;
    const float* cvb = cv_g + b * CV_PER_B;
    const float* chb = ch_g + b * CH_PER_B;
    const float* srcb = src + b * IMG;
    float* dstb = dst + b * IMG;
    float shift = 0.f;
    if (ADD_SHIFT || SUB_SHIFT) shift = (kinv(*key) <= DEPS_) ? DEPS_ : 0.f;
    const int tid = threadIdx.x;
    float v[QPT_F][4], cu[QPT_F][4], cd[QPT_F][4], chq[QPT_F][5];
    int roff[QPT_F], rr[QPT_F], xx[QPT_F];
    bool act[QPT_F];
#pragma unroll
    for (int q = 0; q < QPT_F; ++q) {
        int qi = tid + q * 256;
        act[q] = qi < NQUAD_F;
        int qc = act[q] ? qi : 0;
        int r = qc / NQ_ROW_F;
        int x = (qc - r * NQ_ROW_F) * 4;
        rr[q] = r; xx[q] = x;
        roff[q] = (r + 1) * RW_F + x;
        int gy = y0 - HALO_YF + r, gx = x0 - HALO_XF + x;
        bool gy_in = (gy >= 0) && (gy < HH);
#pragma unroll
        for (int j = 0; j < 4; ++j) {
            int gxx = gx + j;
            bool gx_in = (gxx >= 0) && (gxx < WW);
            bool vin = act[q] && gy_in && gx_in;
            float val = vin ? srcb[gy * WW + gxx] : 0.f;
            if (ADD_SHIFT) val += shift;
            v[q][j] = vin ? val : 0.f;
            bool up_ok = act[q] && (r >= 1) && (gy >= 1) && (gy < HH) && gx_in;
            cu[q][j] = up_ok ? LAM * cvb[(gy - 1) * WW + gxx] : 0.f;
            bool dn_ok = act[q] && (r <= RH_F - 2) && (gy >= 0) && (gy < HH - 1) && gx_in;
            cd[q][j] = dn_ok ? LAM * cvb[gy * WW + gxx] : 0.f;
        }
#pragma unroll
        for (int jj = 0; jj < 5; ++jj) {
            int xe = x + jj, gxe = gx + jj;
            bool ok = act[q] && (xe >= 1) && (xe <= RW_F - 1) && gy_in &&
                      (gxe >= 1) && (gxe < WW);
            chq[q][jj] = ok ? LAM * chb[gy * (WW - 1) + (gxe - 1)] : 0.f;
        }
    }
    for (int i = tid; i < RW_F; i += 256) {
        sb[0][i] = 0.f; sb[0][(RH_F + 1) * RW_F + i] = 0.f;
        sb[1][i] = 0.f; sb[1][(RH_F + 1) * RW_F + i] = 0.f;
    }
#pragma unroll
    for (int q = 0; q < QPT_F; ++q)
        if (act[q])
            *reinterpret_cast<float4*>(&sb[0][roff[q]]) =
                float4{v[q][0], v[q][1], v[q][2], v[q][3]};
    __syncthreads();
    int cur = 0;
    for (int it = 0; it < T_FUSE; ++it) {
        float nv[QPT_F][4];
#pragma unroll
        for (int q = 0; q < QPT_F; ++q) {
            const float* sp = sb[cur];
            float4 up = *reinterpret_cast<const float4*>(&sp[roff[q] - RW_F]);
            float4 dn = *reinterpret_cast<const float4*>(&sp[roff[q] + RW_F]);
            float lf = sp[roff[q] - 1];
            float rt = sp[roff[q] + 4];
            float c0 = v[q][0], c1 = v[q][1], c2 = v[q][2], c3 = v[q][3];
            nv[q][0] = c0 - cu[q][0] * (c0 - up.x) + cd[q][0] * (dn.x - c0)
                          - chq[q][0] * (c0 - lf) + chq[q][1] * (c1 - c0);
            nv[q][1] = c1 - cu[q][1] * (c1 - up.y) + cd[q][1] * (dn.y - c1)
                          - chq[q][1] * (c1 - c0) + chq[q][2] * (c2 - c1);
            nv[q][2] = c2 - cu[q][2] * (c2 - up.z) + cd[q][2] * (dn.z - c2)
                          - chq[q][2] * (c2 - c1) + chq[q][3] * (c3 - c2);
            nv[q][3] = c3 - cu[q][3] * (c3 - up.w) + cd[q][3] * (dn.w - c3)
                          - chq[q][3] * (c3 - c2) + chq[q][4] * (rt - c3);
        }
        int nxt = cur ^ 1;
#pragma unroll
        for (int q = 0; q < QPT_F; ++q) {
            if (act[q])
                *reinterpret_cast<float4*>(&sb[nxt][roff[q]]) =
                    float4{nv[q][0], nv[q][1], nv[q][2], nv[q][3]};
            v[q][0] = nv[q][0]; v[q][1] = nv[q][1];
            v[q][2] = nv[q][2]; v[q][3] = nv[q][3];
        }
        cur = nxt;
        __syncthreads();
    }
#pragma unroll
    for (int q = 0; q < QPT_F; ++q) {
        if (!act[q]) continue;
        int r = rr[q], x = xx[q];
        if (r >= HALO_YF && r < HALO_YF + TILE_HF && x >= HALO_XF && x < HALO_XF + TILE_WF) {
            int gy = y0 - HALO_YF + r, gx = x0 - HALO_XF + x;
            float4 o{v[q][0], v[q][1], v[q][2], v[q][3]};
            if (SUB_SHIFT) { o.x -= shift; o.y -= shift; o.z -= shift; o.w -= shift; }
            *reinterpret_cast<float4*>(dstb + gy * WW + gx) = o;
        }
    }
}

extern "C" void kernel_launch(void* const* d_in, const int* in_sizes, int n_in,
                              void* d_out, int out_size, void* d_ws, size_t ws_size,
                              hipStream_t stream) {
    const float* guide   = (const float*)d_in[0];
    const float* initial = (const float*)d_in[1];
    float* out    = (float*)d_out;
    float* out_y  = out;
    float* out_cv = out + N_DEPTH;
    float* out_ch = out + N_DEPTH + N_CV;

    unsigned* key = (unsigned*)d_ws;
    float* wsf    = (float*)d_ws;
    float* bufA   = wsf + 64;
    float* bufB   = bufA + N_DEPTH;
    float* planes = bufB + N_DEPTH;

    const size_t need = (size_t)(64 + 2 * N_DEPTH + NB * PLANE_IMG) * 4;
    const bool fast = ws_size >= need;

    hipLaunchKernelGGL(init_key_kernel, dim3(1), dim3(1), 0, stream, key);
    hipLaunchKernelGGL(min_kernel, dim3(256), dim3(256), 0, stream, initial, key);

    int nco = N_CV + N_CH;
    hipLaunchKernelGGL(coeff_kernel, dim3((nco + 255) / 256), dim3(256), 0, stream,
                       guide, out_cv, out_ch);
    if (fast) {
        int ntp = NB * PLANE_IMG;
        hipLaunchKernelGGL(prep_planes, dim3((ntp + 255) / 256), dim3(256), 0, stream,
                           out_cv, out_ch, planes);
    }

    float* bufs[2] = {bufA, bufB};
    if (fast) {
        for (int k = 0; k < NSS; ++k) {
            const float* src = (k == 0) ? initial : bufs[(k + 1) & 1];
            float*       dst = (k == NSS - 1) ? out_y : bufs[k & 1];
            if (k == 0)
                hipLaunchKernelGGL((step_wave<true, false>), dim3(NBLK), dim3(NT), 0,
                                   stream, src, dst, planes, key);
            else if (k == NSS - 1)
                hipLaunchKernelGGL((step_wave<false, true>), dim3(NBLK), dim3(NT), 0,
                                   stream, src, dst, planes, key);
            else
                hipLaunchKernelGGL((step_wave<false, false>), dim3(NBLK), dim3(NT), 0,
                                   stream, src, dst, planes, key);
        }
    } else {
        for (int k = 0; k < NSS; ++k) {
            const float* src = (k == 0) ? initial : bufs[(k + 1) & 1];
            float*       dst = (k == NSS - 1) ? out_y : bufs[k & 1];
            if (k == 0)
                hipLaunchKernelGGL((step_fused<true, false>), dim3(256), dim3(256), 0,
                                   stream, src, dst, out_cv, out_ch, key);
            else if (k == NSS - 1)
                hipLaunchKernelGGL((step_fused<false, true>), dim3(256), dim3(256), 0,
                                   stream, src, dst, out_cv, out_ch, key);
            else
                hipLaunchKernelGGL((step_fused<false, false>), dim3(256), dim3(256), 0,
                                   stream, src, dst, out_cv, out_ch, key);
        }
    }
}

// Round 9
// 641.179 us; speedup vs baseline: 1.0829x; 1.0829x over previous
//
#include <hip/hip_runtime.h>

// Perona-Malik diffusion, 500 iters = 50 launches x 10 LDS-fused steps.
// Round-9: occupancy attack. Evidence (R4/R5/R7/R8): per-iter time tracks
// waves/CU, not LDS op count -> latency-bound on the LDS round-trip chain.
// Config: core 32x16 tiles, region 56x36, 1024 blocks x 512 threads =
// 4 blocks/CU = 32 waves/CU (max). QPT=1 (504 quads/block). Inner math =
// R4's verified diff form. Coeffs from global zero-padded planes.

#define HH 512
#define WW 512
#define NB 2
static constexpr float LAM   = 0.24f;
static constexpr float KCOND = 0.03f;
static constexpr float DEPS_ = 0.1f;
static constexpr int IMG      = HH * WW;
static constexpr int N_DEPTH  = NB * IMG;
static constexpr int CV_PER_B = (HH - 1) * WW;
static constexpr int CH_PER_B = HH * (WW - 1);
static constexpr int N_CV     = NB * CV_PER_B;
static constexpr int N_CH     = NB * CH_PER_B;

// ---- fast path: 32x16 core, T=10 ----
static constexpr int T_FUSE = 10, NSS = 50;        // 50 x 10 = 500
static constexpr int TILE_W = 32, TILE_H = 16;
static constexpr int HALO_X = 12, HALO_Y = 10;
static constexpr int RW = TILE_W + 2 * HALO_X;     // 56
static constexpr int RH = TILE_H + 2 * HALO_Y;     // 36
static constexpr int NQ_ROW = RW / 4;              // 14
static constexpr int NQUAD  = NQ_ROW * RH;         // 504
static constexpr int NT     = 512;
static constexpr int SSZ    = (RH + 2) * RW;       // 2128 floats (+guard rows)
// tiles: 16 cols x 32 rows = 512 per image, 1024 blocks total

// global zero-padded coefficient planes
static constexpr int PAD  = 16;                    // >= halo
static constexpr int PSTR = WW + 2 * PAD;          // 544
static constexpr int PV_SZ = (HH + 2 * PAD + 1) * PSTR;  // 545*544
static constexpr int PH_SZ = (HH + 2 * PAD) * PSTR;      // 544*544
static constexpr int PLANE_IMG = PV_SZ + PH_SZ;

// ---- fallback geometry (round-2 verified, inline gather) ----
static constexpr int TILE_WF = 64, TILE_HF = 32;
static constexpr int HALO_XF = 12, HALO_YF = 10;
static constexpr int RW_F = TILE_WF + 2 * HALO_XF;  // 88
static constexpr int RH_F = TILE_HF + 2 * HALO_YF;  // 52
static constexpr int NQ_ROW_F = RW_F / 4;           // 22
static constexpr int NQUAD_F  = NQ_ROW_F * RH_F;
static constexpr int QPT_F    = 5;
static constexpr int SSZ_F    = (RH_F + 2) * RW_F;

// ---- monotone float<->uint key for atomic min ----
__device__ __forceinline__ unsigned fkey(float f) {
    unsigned u = __float_as_uint(f);
    return (u & 0x80000000u) ? ~u : (u | 0x80000000u);
}
__device__ __forceinline__ float kinv(unsigned k) {
    return __uint_as_float((k & 0x80000000u) ? (k & 0x7fffffffu) : ~k);
}

__global__ void init_key_kernel(unsigned* key) { *key = 0xFFFFFFFFu; }

__global__ void min_kernel(const float* __restrict__ x, unsigned* key) {
    float m = 3.4e38f;
    for (int idx = blockIdx.x * blockDim.x + threadIdx.x; idx < N_DEPTH;
         idx += gridDim.x * blockDim.x)
        m = fminf(m, x[idx]);
    for (int off = 32; off > 0; off >>= 1) m = fminf(m, __shfl_down(m, off, 64));
    __shared__ float sm[4];
    int lane = threadIdx.x & 63, wv = threadIdx.x >> 6;
    if (lane == 0) sm[wv] = m;
    __syncthreads();
    if (threadIdx.x == 0) {
        float mm = fminf(fminf(sm[0], sm[1]), fminf(sm[2], sm[3]));
        atomicMin(key, fkey(mm));
    }
}

__global__ void coeff_kernel(const float* __restrict__ g, float* __restrict__ cv,
                             float* __restrict__ chh) {
    int idx = blockIdx.x * blockDim.x + threadIdx.x;
    constexpr float kk = KCOND * KCOND;
    if (idx < N_CV) {
        int b = idx / CV_PER_B;
        int r = idx - b * CV_PER_B;
        int i = r >> 9, j = r & (WW - 1);
        const float* gb = g + b * 3 * IMG + i * WW + j;
        float s = 0.f;
#pragma unroll
        for (int c = 0; c < 3; ++c) s += fabsf(gb[c * IMG + WW] - gb[c * IMG]);
        float m = s / 3.0f;
        cv[idx] = 1.0f / (1.0f + (m * m) / kk);
    } else if (idx < N_CV + N_CH) {
        int t = idx - N_CV;
        int b = t / CH_PER_B;
        int r = t - b * CH_PER_B;
        int i = r / (WW - 1);
        int j = r - i * (WW - 1);
        const float* gb = g + b * 3 * IMG + i * WW + j;
        float s = 0.f;
#pragma unroll
        for (int c = 0; c < 3; ++c) s += fabsf(gb[c * IMG + 1] - gb[c * IMG]);
        float m = s / 3.0f;
        chh[t] = 1.0f / (1.0f + (m * m) / kk);
    }
}

// One-time: global zero-padded L*cv / L*ch planes, stride PSTR.
// PV[(gy+PAD)*PSTR + gx+PAD] = L*cv of vertical edge ABOVE image row gy
//   (0 unless 1<=gy<=HH-1, 0<=gx<WW).
// PH[(gy+PAD)*PSTR + gxe+PAD] = L*ch of horizontal edge whose RIGHT px is gxe
//   (0 unless 0<=gy<HH, 1<=gxe<WW).
__global__ void prep_planes(const float* __restrict__ cv_g,
                            const float* __restrict__ ch_g,
                            float* __restrict__ planes) {
    int idx = blockIdx.x * blockDim.x + threadIdx.x;
    int total = NB * PLANE_IMG;
    if (idx >= total) return;
    int b = idx / PLANE_IMG;
    int r = idx - b * PLANE_IMG;
    float* dst = planes + b * PLANE_IMG;
    if (r < PV_SZ) {
        int row = r / PSTR, col = r - row * PSTR;
        int gy = row - PAD, gx = col - PAD;
        bool ok = (gy >= 1) && (gy <= HH - 1) && (gx >= 0) && (gx < WW);
        dst[r] = ok ? LAM * cv_g[b * CV_PER_B + (gy - 1) * WW + gx] : 0.f;
    } else {
        int rr = r - PV_SZ;
        int row = rr / PSTR, col = rr - row * PSTR;
        int gy = row - PAD, gxe = col - PAD;
        bool ok = (gy >= 0) && (gy < HH) && (gxe >= 1) && (gxe < WW);
        dst[r] = ok ? LAM * ch_g[b * CH_PER_B + gy * (WW - 1) + (gxe - 1)] : 0.f;
    }
}

template <bool ADD_SHIFT, bool SUB_SHIFT>
__global__ __launch_bounds__(NT) void step_q1(
    const float* __restrict__ src, float* __restrict__ dst,
    const float* __restrict__ planes, const unsigned* __restrict__ key) {
    __shared__ float sb[2][SSZ];
    const int blk   = blockIdx.x;
    const int b_img = blk >> 9;              // 512 tiles per image
    const int t     = blk & 511;             // 32 tile-rows x 16 tile-cols
    const int y0 = (t >> 4) * TILE_H;
    const int x0 = (t & 15) * TILE_W;
    const float* srcb = src + b_img * IMG;
    const float* PVb  = planes + b_img * PLANE_IMG;
    const float* PHb  = PVb + PV_SZ;

    float shift = 0.f;
    if (ADD_SHIFT || SUB_SHIFT) shift = (kinv(*key) <= DEPS_) ? DEPS_ : 0.f;

    const int  tid = threadIdx.x;
    const bool act = tid < NQUAD;
    const int  q   = act ? tid : 0;
    const int  r   = q / NQ_ROW;
    const int  x   = (q - r * NQ_ROW) * 4;
    const int  roff = (r + 1) * RW + x;      // +1: top guard row
    const int  gy = y0 - HALO_Y + r;
    const int  gx = x0 - HALO_X + x;         // multiple of 4

    float v0 = 0.f, v1 = 0.f, v2 = 0.f, v3 = 0.f;
    float cu[4], cd[4], ch[5];
    int   goff = 0;
    bool  rin = false;

    if (act) {
        const int pbase = (gy + PAD) * PSTR + (gx + PAD);
        float4 a = *reinterpret_cast<const float4*>(&PVb[pbase]);
        float4 d = *reinterpret_cast<const float4*>(&PVb[pbase + PSTR]);
        float4 h = *reinterpret_cast<const float4*>(&PHb[pbase]);
        cu[0] = a.x; cu[1] = a.y; cu[2] = a.z; cu[3] = a.w;
        cd[0] = d.x; cd[1] = d.y; cd[2] = d.z; cd[3] = d.w;
        ch[0] = h.x; ch[1] = h.y; ch[2] = h.z; ch[3] = h.w;
        ch[4] = PHb[pbase + 4];

        rin = ((unsigned)gy < (unsigned)HH) && (gx >= 0) && (gx <= WW - 4);
        goff = rin ? (gy * WW + gx) : 0;
        if (rin) {
            float4 tv = *reinterpret_cast<const float4*>(srcb + goff);
            if (ADD_SHIFT) { tv.x += shift; tv.y += shift; tv.z += shift; tv.w += shift; }
            v0 = tv.x; v1 = tv.y; v2 = tv.z; v3 = tv.w;
        }
    }

    // zero guard rows (top + bottom) of both buffers
    for (int i = tid; i < RW; i += NT) {
        sb[0][i] = 0.f; sb[0][(RH + 1) * RW + i] = 0.f;
        sb[1][i] = 0.f; sb[1][(RH + 1) * RW + i] = 0.f;
    }
    if (act)
        *reinterpret_cast<float4*>(&sb[0][roff]) = float4{v0, v1, v2, v3};
    __syncthreads();

    int cur = 0;
    for (int it = 0; it < T_FUSE; ++it) {
        int nxt = cur ^ 1;
        if (act) {
            const float* s = sb[cur];
            float4 up = *reinterpret_cast<const float4*>(&s[roff - RW]);
            float4 dn = *reinterpret_cast<const float4*>(&s[roff + RW]);
            float  lf = s[roff - 1];
            float  rt = s[roff + 4];
            float n0 = v0 - cu[0] * (v0 - up.x) + cd[0] * (dn.x - v0)
                          - ch[0] * (v0 - lf) + ch[1] * (v1 - v0);
            float n1 = v1 - cu[1] * (v1 - up.y) + cd[1] * (dn.y - v1)
                          - ch[1] * (v1 - v0) + ch[2] * (v2 - v1);
            float n2 = v2 - cu[2] * (v2 - up.z) + cd[2] * (dn.z - v2)
                          - ch[2] * (v2 - v1) + ch[3] * (v3 - v2);
            float n3 = v3 - cu[3] * (v3 - up.w) + cd[3] * (dn.w - v3)
                          - ch[3] * (v3 - v2) + ch[4] * (rt - v3);
            v0 = n0; v1 = n1; v2 = n2; v3 = n3;
            *reinterpret_cast<float4*>(&sb[nxt][roff]) = float4{v0, v1, v2, v3};
        }
        cur = nxt;
        __syncthreads();
    }

    // store interior core (exact after T_FUSE steps)
    if (act && r >= HALO_Y && r < HALO_Y + TILE_H &&
        x >= HALO_X && x < HALO_X + TILE_W) {
        float* dstb = dst + b_img * IMG;
        float4 o{v0, v1, v2, v3};
        if (SUB_SHIFT) { o.x -= shift; o.y -= shift; o.z -= shift; o.w -= shift; }
        *reinterpret_cast<float4*>(dstb + goff) = o;
    }
}

// -------- fallback (round-2 verified, inline gather, 256 threads) --------
template <bool ADD_SHIFT, bool SUB_SHIFT>
__global__ __launch_bounds__(256, 1) void step_fused(
    const float* __restrict__ src, float* __restrict__ dst,
    const float* __restrict__ cv_g, const float* __restrict__ ch_g,
    const unsigned* __restrict__ key) {
    __shared__ float sb[2][SSZ_F];
    const int blk = blockIdx.x;
    const int b = blk >> 7, t = blk & 127;
    const int y0 = (t >> 3) * TILE_HF, x0 = (t & 7) * TILE_WF;
    const float* cvb = cv_g + b * CV_PER_B;
    const float* chb = ch_g + b * CH_PER_B;
    const float* srcb = src + b * IMG;
    float* dstb = dst + b * IMG;
    float shift = 0.f;
    if (ADD_SHIFT || SUB_SHIFT) shift = (kinv(*key) <= DEPS_) ? DEPS_ : 0.f;
    const int tid = threadIdx.x;
    float v[QPT_F][4], cu[QPT_F][4], cd[QPT_F][4], chq[QPT_F][5];
    int roff[QPT_F], rr[QPT_F], xx[QPT_F];
    bool act[QPT_F];
#pragma unroll
    for (int q = 0; q < QPT_F; ++q) {
        int qi = tid + q * 256;
        act[q] = qi < NQUAD_F;
        int qc = act[q] ? qi : 0;
        int r = qc / NQ_ROW_F;
        int x = (qc - r * NQ_ROW_F) * 4;
        rr[q] = r; xx[q] = x;
        roff[q] = (r + 1) * RW_F + x;
        int gy = y0 - HALO_YF + r, gx = x0 - HALO_XF + x;
        bool gy_in = (gy >= 0) && (gy < HH);
#pragma unroll
        for (int j = 0; j < 4; ++j) {
            int gxx = gx + j;
            bool gx_in = (gxx >= 0) && (gxx < WW);
            bool vin = act[q] && gy_in && gx_in;
            float val = vin ? srcb[gy * WW + gxx] : 0.f;
            if (ADD_SHIFT) val += shift;
            v[q][j] = vin ? val : 0.f;
            bool up_ok = act[q] && (r >= 1) && (gy >= 1) && (gy < HH) && gx_in;
            cu[q][j] = up_ok ? LAM * cvb[(gy - 1) * WW + gxx] : 0.f;
            bool dn_ok = act[q] && (r <= RH_F - 2) && (gy >= 0) && (gy < HH - 1) && gx_in;
            cd[q][j] = dn_ok ? LAM * cvb[gy * WW + gxx] : 0.f;
        }
#pragma unroll
        for (int jj = 0; jj < 5; ++jj) {
            int xe = x + jj, gxe = gx + jj;
            bool ok = act[q] && (xe >= 1) && (xe <= RW_F - 1) && gy_in &&
                      (gxe >= 1) && (gxe < WW);
            chq[q][jj] = ok ? LAM * chb[gy * (WW - 1) + (gxe - 1)] : 0.f;
        }
    }
    for (int i = tid; i < RW_F; i += 256) {
        sb[0][i] = 0.f; sb[0][(RH_F + 1) * RW_F + i] = 0.f;
        sb[1][i] = 0.f; sb[1][(RH_F + 1) * RW_F + i] = 0.f;
    }
#pragma unroll
    for (int q = 0; q < QPT_F; ++q)
        if (act[q])
            *reinterpret_cast<float4*>(&sb[0][roff[q]]) =
                float4{v[q][0], v[q][1], v[q][2], v[q][3]};
    __syncthreads();
    int cur = 0;
    for (int it = 0; it < T_FUSE; ++it) {
        float nv[QPT_F][4];
#pragma unroll
        for (int q = 0; q < QPT_F; ++q) {
            const float* sp = sb[cur];
            float4 up = *reinterpret_cast<const float4*>(&sp[roff[q] - RW_F]);
            float4 dn = *reinterpret_cast<const float4*>(&sp[roff[q] + RW_F]);
            float lf = sp[roff[q] - 1];
            float rt = sp[roff[q] + 4];
            float c0 = v[q][0], c1 = v[q][1], c2 = v[q][2], c3 = v[q][3];
            nv[q][0] = c0 - cu[q][0] * (c0 - up.x) + cd[q][0] * (dn.x - c0)
                          - chq[q][0] * (c0 - lf) + chq[q][1] * (c1 - c0);
            nv[q][1] = c1 - cu[q][1] * (c1 - up.y) + cd[q][1] * (dn.y - c1)
                          - chq[q][1] * (c1 - c0) + chq[q][2] * (c2 - c1);
            nv[q][2] = c2 - cu[q][2] * (c2 - up.z) + cd[q][2] * (dn.z - c2)
                          - chq[q][2] * (c2 - c1) + chq[q][3] * (c3 - c2);
            nv[q][3] = c3 - cu[q][3] * (c3 - up.w) + cd[q][3] * (dn.w - c3)
                          - chq[q][3] * (c3 - c2) + chq[q][4] * (rt - c3);
        }
        int nxt = cur ^ 1;
#pragma unroll
        for (int q = 0; q < QPT_F; ++q) {
            if (act[q])
                *reinterpret_cast<float4*>(&sb[nxt][roff[q]]) =
                    float4{nv[q][0], nv[q][1], nv[q][2], nv[q][3]};
            v[q][0] = nv[q][0]; v[q][1] = nv[q][1];
            v[q][2] = nv[q][2]; v[q][3] = nv[q][3];
        }
        cur = nxt;
        __syncthreads();
    }
#pragma unroll
    for (int q = 0; q < QPT_F; ++q) {
        if (!act[q]) continue;
        int r = rr[q], x = xx[q];
        if (r >= HALO_YF && r < HALO_YF + TILE_HF && x >= HALO_XF && x < HALO_XF + TILE_WF) {
            int gy = y0 - HALO_YF + r, gx = x0 - HALO_XF + x;
            float4 o{v[q][0], v[q][1], v[q][2], v[q][3]};
            if (SUB_SHIFT) { o.x -= shift; o.y -= shift; o.z -= shift; o.w -= shift; }
            *reinterpret_cast<float4*>(dstb + gy * WW + gx) = o;
        }
    }
}

extern "C" void kernel_launch(void* const* d_in, const int* in_sizes, int n_in,
                              void* d_out, int out_size, void* d_ws, size_t ws_size,
                              hipStream_t stream) {
    const float* guide   = (const float*)d_in[0];
    const float* initial = (const float*)d_in[1];
    float* out    = (float*)d_out;
    float* out_y  = out;
    float* out_cv = out + N_DEPTH;
    float* out_ch = out + N_DEPTH + N_CV;

    unsigned* key = (unsigned*)d_ws;
    float* wsf    = (float*)d_ws;
    float* bufA   = wsf + 64;
    float* bufB   = bufA + N_DEPTH;
    float* planes = bufB + N_DEPTH;

    const size_t need = (size_t)(64 + 2 * N_DEPTH + NB * PLANE_IMG) * 4;
    const bool fast = ws_size >= need;

    hipLaunchKernelGGL(init_key_kernel, dim3(1), dim3(1), 0, stream, key);
    hipLaunchKernelGGL(min_kernel, dim3(256), dim3(256), 0, stream, initial, key);

    int nco = N_CV + N_CH;
    hipLaunchKernelGGL(coeff_kernel, dim3((nco + 255) / 256), dim3(256), 0, stream,
                       guide, out_cv, out_ch);
    if (fast) {
        int ntp = NB * PLANE_IMG;
        hipLaunchKernelGGL(prep_planes, dim3((ntp + 255) / 256), dim3(256), 0, stream,
                           out_cv, out_ch, planes);
    }

    float* bufs[2] = {bufA, bufB};
    if (fast) {
        for (int k = 0; k < NSS; ++k) {
            const float* src = (k == 0) ? initial : bufs[(k + 1) & 1];
            float*       dst = (k == NSS - 1) ? out_y : bufs[k & 1];
            if (k == 0)
                hipLaunchKernelGGL((step_q1<true, false>), dim3(NB * 512), dim3(NT), 0,
                                   stream, src, dst, planes, key);
            else if (k == NSS - 1)
                hipLaunchKernelGGL((step_q1<false, true>), dim3(NB * 512), dim3(NT), 0,
                                   stream, src, dst, planes, key);
            else
                hipLaunchKernelGGL((step_q1<false, false>), dim3(NB * 512), dim3(NT), 0,
                                   stream, src, dst, planes, key);
        }
    } else {
        for (int k = 0; k < NSS; ++k) {
            const float* src = (k == 0) ? initial : bufs[(k + 1) & 1];
            float*       dst = (k == NSS - 1) ? out_y : bufs[k & 1];
            if (k == 0)
                hipLaunchKernelGGL((step_fused<true, false>), dim3(256), dim3(256), 0,
                                   stream, src, dst, out_cv, out_ch, key);
            else if (k == NSS - 1)
                hipLaunchKernelGGL((step_fused<false, true>), dim3(256), dim3(256), 0,
                                   stream, src, dst, out_cv, out_ch, key);
            else
                hipLaunchKernelGGL((step_fused<false, false>), dim3(256), dim3(256), 0,
                                   stream, src, dst, out_cv, out_ch, key);
        }
    }
}